// Round 12
// baseline (403.027 us; speedup 1.0000x reference)
//
#include <hip/hip_runtime.h>

namespace {
constexpr int N  = 500000;
constexpr long long E = 3000000;
constexpr int C  = 128;
constexpr int M  = 125000;
constexpr int NP = 5;
constexpr int ST = 65536;       // scan3 partial threads
constexpr int NC = 512;         // coarse buckets (key >> 23)
constexpr int PMAX = 8192;      // partition pad (max expected ~6.8k)
constexpr int NSB = 2048;       // sub-buckets per partition ((key>>12)&2047)

// d_out flat layout (float32), reference return order:
constexpr long long O_XF  = 0;          // new_xfinal      M*C
constexpr long long O_NEI = 16000000;   // new_edge_index  2*E
constexpr long long O_POS = 22000000;   // new_pos         M*2
constexpr long long O_IAT = 22250000;   // indexatttennew  M*5
constexpr long long O_NB  = 22875000;   // new_batch       M
constexpr long long O_EIP = 23000000;   // edge_index      2*E
constexpr long long O_CL  = 29000000;   // cluster         N
constexpr long long O_BAT = 29500000;   // batch           N

// fallback scratch overlays in d_out (same as round 11; used only when ws is small)
constexpr long long S_CNT = 23000000;
constexpr long long S_CLU = 23130000;
constexpr long long S_COF = 23640000;
constexpr long long S_RPM = 23770000;
constexpr long long S_PT  = 25320000;
constexpr long long S_PT2 = 25390000;
constexpr long long S_CBN = 25500000;
constexpr long long S_CBS = 25501000;
constexpr long long S_CPS = 25502000;
constexpr long long S_UCT = 25503000;
constexpr long long S_UOF = 25504000;
}

// mode: 1=int64, 3=float64, 0=int32, 2=float32
__global__ void k_detect(const void* __restrict__ ei, int* __restrict__ flag) {
    if (threadIdx.x != 0 || blockIdx.x != 0) return;
    const unsigned long long* q = (const unsigned long long*)ei;
    unsigned long long hi = 0, lo = 0;
    for (int i = 0; i < 64; ++i) {
        unsigned long long a = q[i];
        unsigned long long b = q[(size_t)E / 2 + i];
        hi |= (a >> 32) | (b >> 32);
        lo |= (a & 0xffffffffULL) | (b & 0xffffffffULL);
    }
    int mode;
    if (hi == 0) mode = 1;
    else if (lo == 0) mode = 3;
    else {
        const int* p = (const int*)ei;
        int ok = 1;
        for (int i = 0; i < 256; ++i) {
            int v0 = p[i], v1 = p[E + i];
            if (v0 < 0 || v0 >= N || v1 < 0 || v1 >= N) ok = 0;
        }
        mode = ok ? 0 : 2;
    }
    *flag = mode;
}

__device__ __forceinline__ int load_ei(const void* ei, long long idx, int mode) {
    long long v;
    if (mode == 1)      v = ((const long long*)ei)[idx];
    else if (mode == 0) v = (long long)((const int*)ei)[idx];
    else if (mode == 3) v = (long long)(((const double*)ei)[idx]);
    else                v = (long long)(((const float*)ei)[idx]);
    if (v < 0 || v >= N) v = 0;
    return (int)v;
}

// int32-wraparound key (JAX x64-disabled), biased: unsigned cmp == signed cmp
__device__ __forceinline__ unsigned make_key(int c0, int c1) {
    unsigned uv = (unsigned)c0 * (unsigned)M + (unsigned)c1;
    return uv ^ 0x80000000u;
}

__global__ void k_rows(const float* __restrict__ iat, const float* __restrict__ batch,
                       const int* __restrict__ pool, float* __restrict__ out,
                       int* __restrict__ clu, int* __restrict__ cnt) {
    int i = blockIdx.x * blockDim.x + threadIdx.x;
    if (i >= N) return;
    int p = pool[0];
    int c = (int)iat[(long long)i * NP + p];
    clu[i] = c;
    out[O_CL + i] = (float)c;
    out[O_BAT + i] = batch[i];
    atomicAdd(cnt + c, 1);
}

// ---- 3-level exclusive scan ----
__global__ void k_scan_part(const int* __restrict__ in, int* __restrict__ pt, int n) {
    int t = blockIdx.x * blockDim.x + threadIdx.x;
    int chunk = (n + ST - 1) / ST;
    int s = t * chunk, e = s + chunk;
    if (s > n) s = n;
    if (e > n) e = n;
    int sum = 0;
    for (int i = s; i < e; ++i) sum += in[i];
    pt[t] = sum;
}

__global__ void k_scan1(const int* __restrict__ in, int* __restrict__ outp, int n) {
    __shared__ int sh[1024];
    int tid = threadIdx.x;
    int chunk = (n + 1023) / 1024;
    int start = tid * chunk, end = start + chunk;
    if (start > n) start = n;
    if (end > n) end = n;
    int s = 0;
    for (int i = start; i < end; ++i) s += in[i];
    sh[tid] = s;
    __syncthreads();
    for (int off = 1; off < 1024; off <<= 1) {
        int v = (tid >= off) ? sh[tid - off] : 0;
        __syncthreads();
        sh[tid] += v;
        __syncthreads();
    }
    int run = (tid == 0) ? 0 : sh[tid - 1];
    for (int i = start; i < end; ++i) { outp[i] = run; run += in[i]; }
    if (tid == 1023) outp[n] = sh[1023];
}

__global__ void k_scan_out(const int* __restrict__ in, const int* __restrict__ pt2,
                           int* __restrict__ outp, int n) {
    int t = blockIdx.x * blockDim.x + threadIdx.x;
    int run = pt2[t];
    int chunk = (n + ST - 1) / ST;
    int s = t * chunk, e = s + chunk;
    if (s > n) s = n;
    if (e > n) e = n;
    for (int i = s; i < e; ++i) { outp[i] = run; run += in[i]; }
    if (t == ST - 1) outp[n] = run;
}

__global__ void k_rowscatter(const int* __restrict__ clu, int* __restrict__ cof,
                             int* __restrict__ rpm) {
    int i = blockIdx.x * blockDim.x + threadIdx.x;
    if (i >= N) return;
    int c = clu[i];
    int pos = atomicAdd(cof + c, 1);
    rpm[pos] = i;
}

// one wave per cluster; rpm chunk pre-loaded + shfl broadcast; 8 row-groups of
// 8 lanes, 4 float4/lane interleaved so each load inst = 1 cache line per row
__global__ void k_xmean(const float4* __restrict__ x4, float* __restrict__ out,
                        const int* __restrict__ cof, const int* __restrict__ rpm) {
    long long t = (long long)blockIdx.x * blockDim.x + threadIdx.x;
    int wid = (int)(t >> 6);
    int lane = threadIdx.x & 63;
    if (wid >= M) return;
    int start = (wid == 0) ? 0 : cof[wid - 1];
    int end = cof[wid];
    int cnt = end - start;
    float fcnt = (float)cnt;
    if (fcnt < 1.0f) fcnt = 1.0f;
    int g = lane >> 3;        // row group 0..7
    int sub = lane & 7;       // float4 lane within line
    float4 a0 = make_float4(0.f, 0.f, 0.f, 0.f);
    float4 a1 = a0, a2 = a0, a3 = a0;
    for (int cb = 0; cb < cnt; cb += 64) {
        int rem = cnt - cb;
        if (rem > 64) rem = 64;
        int rl = (lane < rem) ? rpm[start + cb + lane] : 0;
        for (int r = g; r < rem; r += 8) {
            int row = __shfl(rl, r, 64);
            const float4* rb = x4 + (long long)row * 32 + sub;
            float4 v0 = rb[0];
            float4 v1 = rb[8];
            float4 v2 = rb[16];
            float4 v3 = rb[24];
            a0.x += v0.x; a0.y += v0.y; a0.z += v0.z; a0.w += v0.w;
            a1.x += v1.x; a1.y += v1.y; a1.z += v1.z; a1.w += v1.w;
            a2.x += v2.x; a2.y += v2.y; a2.z += v2.z; a2.w += v2.w;
            a3.x += v3.x; a3.y += v3.y; a3.z += v3.z; a3.w += v3.w;
        }
    }
#define XRED(K) \
    a0.x += __shfl_xor(a0.x, K, 64); a0.y += __shfl_xor(a0.y, K, 64); \
    a0.z += __shfl_xor(a0.z, K, 64); a0.w += __shfl_xor(a0.w, K, 64); \
    a1.x += __shfl_xor(a1.x, K, 64); a1.y += __shfl_xor(a1.y, K, 64); \
    a1.z += __shfl_xor(a1.z, K, 64); a1.w += __shfl_xor(a1.w, K, 64); \
    a2.x += __shfl_xor(a2.x, K, 64); a2.y += __shfl_xor(a2.y, K, 64); \
    a2.z += __shfl_xor(a2.z, K, 64); a2.w += __shfl_xor(a2.w, K, 64); \
    a3.x += __shfl_xor(a3.x, K, 64); a3.y += __shfl_xor(a3.y, K, 64); \
    a3.z += __shfl_xor(a3.z, K, 64); a3.w += __shfl_xor(a3.w, K, 64);
    XRED(8) XRED(16) XRED(32)
#undef XRED
    if (lane < 8) {
        float4* ob = (float4*)(out + O_XF) + (long long)wid * 32 + sub;
        float4 o;
        o.x = a0.x / fcnt; o.y = a0.y / fcnt; o.z = a0.z / fcnt; o.w = a0.w / fcnt;
        ob[0] = o;
        o.x = a1.x / fcnt; o.y = a1.y / fcnt; o.z = a1.z / fcnt; o.w = a1.w / fcnt;
        ob[8] = o;
        o.x = a2.x / fcnt; o.y = a2.y / fcnt; o.z = a2.z / fcnt; o.w = a2.w / fcnt;
        ob[16] = o;
        o.x = a3.x / fcnt; o.y = a3.y / fcnt; o.z = a3.z / fcnt; o.w = a3.w / fcnt;
        ob[24] = o;
    }
}

// small-column means: one thread per (cluster, col); inputs L2/L3-resident
__global__ void k_smallmean(const float* __restrict__ xpos, const float* __restrict__ iat,
                            const float* __restrict__ batch, float* __restrict__ out,
                            const int* __restrict__ cof, const int* __restrict__ rpm) {
    int t = blockIdx.x * blockDim.x + threadIdx.x;
    if (t >= M * 8) return;
    int m = t >> 3;
    int lc = t & 7;
    int start = (m == 0) ? 0 : cof[m - 1];
    int end = cof[m];
    float cnt = (float)(end - start);
    if (cnt < 1.0f) cnt = 1.0f;
    float s = 0.0f;
    for (int r = start; r < end; ++r) {
        int row = rpm[r];
        float v;
        if (lc < 2)      v = xpos[(long long)row * 2 + lc];
        else if (lc < 7) v = iat[(long long)row * NP + (lc - 2)];
        else             v = batch[row];
        s += v;
    }
    float mres = s / cnt;
    if (lc >= 2) mres = truncf(mres);
    if (lc < 2)      out[O_POS + (long long)m * 2 + lc] = mres;
    else if (lc < 7) out[O_IAT + (long long)m * NP + (lc - 2)] = mres;
    else             out[O_NB + m] = mres;
}

// stage keys + coarse histogram; optionally fused edge_index passthrough
__global__ __launch_bounds__(256) void k_edges2(const void* __restrict__ ei,
                                                const int* __restrict__ flag,
                                                const int* __restrict__ clu,
                                                unsigned* __restrict__ stage,
                                                int* __restrict__ cbn,
                                                float* __restrict__ out, int fuse) {
    __shared__ int h[NC];
    int tid = threadIdx.x;
    long long cb = (long long)blockIdx.x * 4096;
    for (int s = tid; s < NC; s += 256) h[s] = 0;
    __syncthreads();
    int mode = *flag;
    for (int s = 0; s < 16; ++s) {
        long long i = cb + s * 256 + tid;
        if (i < E) {
            int e0 = load_ei(ei, i, mode);
            int e1 = load_ei(ei, E + i, mode);
            if (fuse) {
                out[O_EIP + i]     = (float)e0;
                out[O_EIP + E + i] = (float)e1;
            }
            unsigned key = make_key(clu[e0], clu[e1]);
            stage[i] = key;
            atomicAdd(&h[key >> 23], 1);
        }
    }
    __syncthreads();
    for (int s = tid; s < NC; s += 256) {
        int v = h[s];
        if (v) atomicAdd(cbn + s, v);
    }
}

// single-block exclusive scan of NC=512; optionally seeds pos (reservation)
__global__ void k_scan512(const int* __restrict__ in, int* __restrict__ o,
                          int* __restrict__ pos) {
    __shared__ int sh[NC];
    int tid = threadIdx.x;
    int v0 = in[tid];
    sh[tid] = v0;
    __syncthreads();
    for (int off = 1; off < NC; off <<= 1) {
        int v = (tid >= off) ? sh[tid - off] : 0;
        __syncthreads();
        sh[tid] += v;
        __syncthreads();
    }
    int excl = sh[tid] - v0;
    o[tid] = excl;
    if (pos) pos[tid] = excl;
    if (tid == NC - 1) o[NC] = sh[NC - 1];
}

// LDS-aggregated partition into coarse-bucket runs
__global__ __launch_bounds__(512) void k_part(const unsigned* __restrict__ stage,
                                              int* __restrict__ cps,
                                              unsigned* __restrict__ bdata) {
    __shared__ int h[NC], h2[NC], lb[NC], gb[NC];
    __shared__ unsigned g[4096];
    __shared__ int d[4096];
    int tid = threadIdx.x;
    long long cb = (long long)blockIdx.x * 4096;
    if (tid < NC) { h[tid] = 0; h2[tid] = 0; }
    __syncthreads();
    unsigned keys[8];
    for (int s = 0; s < 8; ++s) {
        long long i = cb + s * 512 + tid;
        if (i < E) {
            unsigned key = stage[i];
            keys[s] = key;
            atomicAdd(&h[key >> 23], 1);
        }
    }
    __syncthreads();
    if (tid < NC) lb[tid] = h[tid];
    __syncthreads();
    for (int off = 1; off < NC; off <<= 1) {
        int v = (tid < NC && tid >= off) ? lb[tid - off] : 0;
        __syncthreads();
        if (tid < NC) lb[tid] += v;
        __syncthreads();
    }
    if (tid < NC) {
        int excl = lb[tid] - h[tid];
        gb[tid] = atomicAdd(cps + tid, h[tid]);
        lb[tid] = excl;
    }
    __syncthreads();
    for (int s = 0; s < 8; ++s) {
        long long i = cb + s * 512 + tid;
        if (i < E) {
            unsigned key = keys[s];
            int b = key >> 23;
            int r = atomicAdd(&h2[b], 1);
            int slot = lb[b] + r;
            g[slot] = key;
            d[slot] = gb[b] + r;
        }
    }
    __syncthreads();
    int tot = (int)((E - cb < 4096) ? (E - cb) : 4096);
    for (int s = 0; s < 8; ++s) {
        int slot = tid + s * 512;
        if (slot < tot) bdata[d[slot]] = g[slot];
    }
}

// per-partition MSD sub-bucket sort + dedupe-compact (in place)
__global__ __launch_bounds__(1024) void k_psort(const int* __restrict__ cbs,
                                                unsigned* __restrict__ bdata,
                                                int* __restrict__ uct) {
    __shared__ unsigned sk2[PMAX];
    __shared__ int hist[NSB];
    __shared__ int hstart[NSB];
    __shared__ int ssc[1024];
    int p = blockIdx.x;
    int tid = threadIdx.x;
    int base = cbs[p];
    int n = cbs[p + 1] - base;
    if (n > PMAX) n = PMAX;
    for (int i = tid; i < NSB; i += 1024) hist[i] = 0;
    __syncthreads();
    for (int i = tid; i < n; i += 1024)
        atomicAdd(&hist[(bdata[base + i] >> 12) & (NSB - 1)], 1);
    __syncthreads();
    int h0 = hist[2 * tid], h1 = hist[2 * tid + 1];
    ssc[tid] = h0 + h1;
    __syncthreads();
    for (int off = 1; off < 1024; off <<= 1) {
        int v = (tid >= off) ? ssc[tid - off] : 0;
        __syncthreads();
        ssc[tid] += v;
        __syncthreads();
    }
    int excl = ssc[tid] - (h0 + h1);
    hstart[2 * tid] = excl;      hstart[2 * tid + 1] = excl + h0;
    __syncthreads();
    hist[2 * tid] = excl;        hist[2 * tid + 1] = excl + h0;
    __syncthreads();
    for (int i = tid; i < n; i += 1024) {
        unsigned k = bdata[base + i];
        int b = (k >> 12) & (NSB - 1);
        int r = atomicAdd(&hist[b], 1);
        sk2[r] = k;
    }
    __syncthreads();
    for (int bb = 0; bb < 2; ++bb) {
        int b = 2 * tid + bb;
        int s = hstart[b];
        int e = hist[b];
        for (int i = s + 1; i < e; ++i) {
            unsigned v = sk2[i];
            int j = i - 1;
            while (j >= s && sk2[j] > v) { sk2[j + 1] = sk2[j]; --j; }
            sk2[j + 1] = v;
        }
    }
    __syncthreads();
    int chunk = (n + 1023) / 1024;
    int cs = tid * chunk, ce = cs + chunk;
    if (cs > n) cs = n;
    if (ce > n) ce = n;
    int c = 0;
    for (int i = cs; i < ce; ++i)
        if (i == 0 || sk2[i] != sk2[i - 1]) ++c;
    ssc[tid] = c;
    __syncthreads();
    for (int off = 1; off < 1024; off <<= 1) {
        int v = (tid >= off) ? ssc[tid - off] : 0;
        __syncthreads();
        ssc[tid] += v;
        __syncthreads();
    }
    int pos = ssc[tid] - c;
    for (int i = cs; i < ce; ++i)
        if (i == 0 || sk2[i] != sk2[i - 1]) bdata[base + pos++] = sk2[i];
    if (tid == 1023) uct[p] = ssc[1023];
}

// copy each partition's sorted unique keys to final position, decoded
__global__ __launch_bounds__(256) void k_uwrite2(const int* __restrict__ cbs,
                                                 const int* __restrict__ uct,
                                                 const int* __restrict__ uof,
                                                 const unsigned* __restrict__ bdata,
                                                 float* __restrict__ out) {
    int p = blockIdx.x;
    int tid = threadIdx.x;
    int base = cbs[p];
    int u = uct[p];
    long long dst = uof[p];
    for (int i = tid; i < u; i += 256) {
        unsigned v = bdata[base + i];
        long long k = (long long)(int)(v ^ 0x80000000u);
        long long r = k % M; if (r < 0) r += M;
        long long q = (k - r) / M;
        out[O_NEI + dst + i]     = (float)q;
        out[O_NEI + E + dst + i] = (float)r;
    }
}

// tail fill = last sorted unique pair (== keys.max())
__global__ void k_fill(const int* __restrict__ uof, float* __restrict__ out) {
    int p = blockIdx.x * blockDim.x + threadIdx.x;
    if (p >= E) return;
    int U = uof[NC];
    if (p < U) return;
    float r0 = out[O_NEI + U - 1];
    float r1 = out[O_NEI + E + U - 1];
    out[O_NEI + p]     = r0;
    out[O_NEI + E + p] = r1;
}

// edge_index passthrough — fallback path only
__global__ void k_pass(const void* __restrict__ ei, const int* __restrict__ flag,
                       float* __restrict__ out) {
    int e = blockIdx.x * blockDim.x + threadIdx.x;
    if (e >= E) return;
    int mode = *flag;
    out[O_EIP + e]     = (float)load_ei(ei, e, mode);
    out[O_EIP + E + e] = (float)load_ei(ei, E + e, mode);
}

extern "C" void kernel_launch(void* const* d_in, const int* in_sizes, int n_in,
                              void* d_out, int out_size, void* d_ws, size_t ws_size,
                              hipStream_t stream) {
    const float* x     = (const float*)d_in[0];
    const void*  ei    = d_in[1];
    const float* xpos  = (const float*)d_in[2];
    const float* iat   = (const float*)d_in[3];
    const float* batch = (const float*)d_in[4];
    const int*   pool  = (const int*)d_in[5];
    float* out = (float*)d_out;
    unsigned* stage = (unsigned*)(out + O_NEI);

    bool usew = ws_size >= (size_t)18000000;   // ~17.6 MB needed for ws scratch
    int *cnt, *clu, *cof, *rpm, *pt, *pt2, *cbn, *cbs, *cps, *uct, *uof, *flag;
    unsigned* bdata;
    int fuse;
    if (usew) {
        int* W = (int*)d_ws;
        cnt = W;                 // M
        clu = W + 125000;        // N
        cof = W + 625024;        // M+1
        rpm = W + 750080;        // N
        pt  = W + 1250112;       // ST
        pt2 = W + 1315712;       // ST+1
        cbn = W + 1381312;       // NC
        cbs = W + 1381888;       // NC+1
        cps = W + 1382464;       // NC
        uct = W + 1383040;       // NC
        uof = W + 1383616;       // NC+1
        bdata = (unsigned*)(W + 1384192);   // E
        flag = W + 4384256;
        fuse = 1;
    } else {
        cnt = (int*)(out + S_CNT); clu = (int*)(out + S_CLU);
        cof = (int*)(out + S_COF); rpm = (int*)(out + S_RPM);
        pt  = (int*)(out + S_PT);  pt2 = (int*)(out + S_PT2);
        cbn = (int*)(out + S_CBN); cbs = (int*)(out + S_CBS);
        cps = (int*)(out + S_CPS); uct = (int*)(out + S_UCT);
        uof = (int*)(out + S_UOF);
        bdata = (unsigned*)(out + O_EIP + E);
        flag = (int*)d_ws;
        fuse = 0;
    }

    int eblocks = (int)((E + 4095) / 4096);   // 733

    hipMemsetAsync(cnt, 0, (size_t)M * 4, stream);
    hipMemsetAsync(cbn, 0, (size_t)NC * 4, stream);

    k_detect<<<1, 64, 0, stream>>>(ei, flag);
    k_rows<<<(N + 255) / 256, 256, 0, stream>>>(iat, batch, pool, out, clu, cnt);
    k_scan_part<<<ST / 256, 256, 0, stream>>>(cnt, pt, M);
    k_scan1<<<1, 1024, 0, stream>>>(pt, pt2, ST);
    k_scan_out<<<ST / 256, 256, 0, stream>>>(cnt, pt2, cof, M);
    k_rowscatter<<<(N + 255) / 256, 256, 0, stream>>>(clu, cof, rpm);

    long long txm = (long long)M * 64;
    k_xmean<<<(unsigned)((txm + 255) / 256), 256, 0, stream>>>(
        (const float4*)x, out, cof, rpm);
    k_smallmean<<<(M * 8 + 255) / 256, 256, 0, stream>>>(xpos, iat, batch, out, cof, rpm);

    k_edges2<<<eblocks, 256, 0, stream>>>(ei, flag, clu, stage, cbn, out, fuse);
    k_scan512<<<1, NC, 0, stream>>>(cbn, cbs, cps);
    k_part<<<eblocks, 512, 0, stream>>>(stage, cps, bdata);
    k_psort<<<NC, 1024, 0, stream>>>(cbs, bdata, uct);
    k_scan512<<<1, NC, 0, stream>>>(uct, uof, (int*)nullptr);
    k_uwrite2<<<NC, 256, 0, stream>>>(cbs, uct, uof, bdata, out);
    k_fill<<<(unsigned)((E + 255) / 256), 256, 0, stream>>>(uof, out);
    if (!fuse) k_pass<<<(unsigned)((E + 255) / 256), 256, 0, stream>>>(ei, flag, out);
}